// Round 14
// baseline (287.500 us; speedup 1.0000x reference)
//
#include <hip/hip_runtime.h>
#include <math.h>

#define EPSV 1e-6f
#define NTOK 8192
#define NE   16384
#define DIM  256

using short8 = __attribute__((ext_vector_type(8))) short;
using f32x4v = __attribute__((ext_vector_type(4))) float;

__device__ __forceinline__ unsigned short f2bf(float v) {
    unsigned int u = __float_as_uint(v);
    u += 0x7fffu + ((u >> 16) & 1u);   // RNE
    return (unsigned short)(u >> 16);
}
__device__ __forceinline__ float bf2f(unsigned short h) {
    return __uint_as_float(((unsigned int)h) << 16);
}

__device__ __forceinline__ void gload_lds16(const void* g, void* s) {
    __builtin_amdgcn_global_load_lds(
        (const __attribute__((address_space(1))) void*)g,
        (__attribute__((address_space(3))) void*)s, 16, 0, 0);
}

// split 8 consecutive fp32 into bf16 hi/lo fragments
__device__ __forceinline__ void split8(const float4 a, const float4 b,
                                       short8& h, short8& l) {
    float f[8] = {a.x, a.y, a.z, a.w, b.x, b.y, b.z, b.w};
#pragma unroll
    for (int j = 0; j < 8; ++j) {
        unsigned short hh = f2bf(f[j]);
        h[j] = (short)hh;
        l[j] = (short)f2bf(f[j] - bf2f(hh));
    }
}

// ---------------------------------------------------------------- K0c+fZ:
// blocks [0,256): emb = codebook @ W.T via 4-term bf16x2 MFMA + bf16
//   split + per-c-tile se partials (nb=bid&127 -> n0, cb=bid>>7 -> c0).
//   R13: W staged as RAW FP32 (32 KB, same footprint as old wh+wl) and
//   split8 applied on the B side after ds_read — bit-identical Bh/Bl to
//   the old pre-split path; the separate fW kernel is eliminated.
// blocks [256,384): z transpose + bf16 split + per-token sz (fp64).
__global__ __launch_bounds__(256, 2) void k0c_fz(
    const float* __restrict__ cb, const float* __restrict__ Wm,
    float* __restrict__ emb,
    unsigned short* __restrict__ eh, unsigned short* __restrict__ el,
    float* __restrict__ se0, float* __restrict__ se1,
    const float* __restrict__ zin, float* __restrict__ z_flat,
    unsigned short* __restrict__ zh, unsigned short* __restrict__ zl,
    float* __restrict__ sz) {
    __shared__ char smemU[65536];
    const int bid = blockIdx.x;
    const int tid = threadIdx.x;

    if (bid >= 256) {                  // ---- fZ: z transpose + split + sz
        float (*tile)[65] = (float(*)[65])smemU;   // 16.6 KB of smemU
        const int zbid = bid - 256;
        const int yx0 = (zbid & 15) * 64, b = zbid >> 4;
        const int sub = tid >> 6, ln = tid & 63;
        double dacc[16];
#pragma unroll
        for (int j = 0; j < 16; ++j) dacc[j] = 0.0;

        for (int cc = 0; cc < 4; ++cc) {
            const int c0 = cc * 64;
            __syncthreads();
#pragma unroll
            for (int j = 0; j < 16; ++j) {
                int cl = j * 4 + sub;
                tile[cl][ln] = zin[((size_t)(b * 256 + c0 + cl) << 10) + yx0 + ln];
            }
            __syncthreads();
#pragma unroll
            for (int j = 0; j < 16; ++j) {
                int tl = j * 4 + sub;
                float v = tile[ln][tl];
                size_t o = (size_t)(b * 1024 + yx0 + tl) * 256 + c0 + ln;
                z_flat[o] = v;
                unsigned short h = f2bf(v);
                zh[o] = h;
                zl[o] = f2bf(v - bf2f(h));
                dacc[j] += (double)v * v;
            }
        }
#pragma unroll
        for (int j = 0; j < 16; ++j) {
            double s = dacc[j];
#pragma unroll
            for (int m = 1; m < 64; m <<= 1) s += __shfl_xor(s, m);
            if (ln == 0) sz[b * 1024 + yx0 + j * 4 + sub] = (float)s;
        }
        return;
    }

    // ---- k0c: emb GEMM
    char* smemC = smemU;
    const int w = tid >> 6, lane = tid & 63;
    const int quad = lane >> 4, lr = lane & 15;
    const int wr = w & 1, wc = w >> 1;
    const int nb = bid & 127, cbi = bid >> 7;
    const int n0 = nb * 128, c0 = cbi * 128;

    f32x4v acc[4][4];
#pragma unroll
    for (int mt = 0; mt < 4; ++mt)
#pragma unroll
        for (int nt = 0; nt < 4; ++nt)
            acc[mt][nt] = (f32x4v){0.f, 0.f, 0.f, 0.f};

    for (int kc = 0; kc < 4; ++kc) {
        __syncthreads();
#pragma unroll
        for (int i = 0; i < 16; ++i) {
            int s = i * 4 + w;           // wave-uniform segment 0..63
            int u = s * 64 + lane;       // global unit 0..4095
            const void* g;
            if (s < 32) {                // cbS: [kg(16)][row(128)] fp32x4
                int kg = u >> 7, row = u & 127;
                g = cb + (size_t)(n0 + row) * 256 + kc * 64 + kg * 4;
            } else {                     // wS: [kg(16)][row(128)] fp32x4
                int u1 = u - 2048;
                int kg = u1 >> 7, row = u1 & 127;
                g = Wm + (size_t)(c0 + row) * 256 + kc * 64 + kg * 4;
            }
            gload_lds16(g, smemC + ((size_t)u << 4));
        }
        __syncthreads();
#pragma unroll
        for (int ks = 0; ks < 2; ++ks) {
            short8 Ah[4], Al[4], Bh[4], Bl[4];
#pragma unroll
            for (int mt = 0; mt < 4; ++mt) {
                int m = wr * 64 + mt * 16 + lr;
                int kg2 = ks * 8 + quad * 2;
                float4 f0 = *(const float4*)(smemC + (((size_t)kg2 * 128 + m) << 4));
                float4 f1 = *(const float4*)(smemC + ((((size_t)kg2 + 1) * 128 + m) << 4));
                split8(f0, f1, Ah[mt], Al[mt]);
            }
#pragma unroll
            for (int nt = 0; nt < 4; ++nt) {
                int n = wc * 64 + nt * 16 + lr;
                int kg2 = ks * 8 + quad * 2;
                float4 f0 = *(const float4*)(smemC + (((size_t)2048 + kg2 * 128 + n) << 4));
                float4 f1 = *(const float4*)(smemC + (((size_t)2048 + (kg2 + 1) * 128 + n) << 4));
                split8(f0, f1, Bh[nt], Bl[nt]);
            }
#pragma unroll
            for (int mt = 0; mt < 4; ++mt)
#pragma unroll
                for (int nt = 0; nt < 4; ++nt) {
                    f32x4v a = acc[mt][nt];
                    a = __builtin_amdgcn_mfma_f32_16x16x32_bf16(Ah[mt], Bh[nt], a, 0, 0, 0);
                    a = __builtin_amdgcn_mfma_f32_16x16x32_bf16(Ah[mt], Bl[nt], a, 0, 0, 0);
                    a = __builtin_amdgcn_mfma_f32_16x16x32_bf16(Al[mt], Bh[nt], a, 0, 0, 0);
                    a = __builtin_amdgcn_mfma_f32_16x16x32_bf16(Al[mt], Bl[nt], a, 0, 0, 0);
                    acc[mt][nt] = a;
                }
        }
    }
#pragma unroll
    for (int mt = 0; mt < 4; ++mt)
#pragma unroll
        for (int rr = 0; rr < 4; ++rr) {
            int row = n0 + wr * 64 + mt * 16 + quad * 4 + rr;
#pragma unroll
            for (int nt = 0; nt < 4; ++nt) {
                int col = c0 + wc * 64 + nt * 16 + lr;
                size_t o = (size_t)row * 256 + col;
                float v = acc[mt][nt][rr];
                emb[o] = v;
                unsigned short h = f2bf(v);
                eh[o] = h;
                el[o] = f2bf(v - bf2f(h));
            }
        }
    // ---- se partial over this block's 128 cols
    __syncthreads();
    float* sblk = (float*)smemC;       // [2][128]
#pragma unroll
    for (int mt = 0; mt < 4; ++mt)
#pragma unroll
        for (int rr = 0; rr < 4; ++rr) {
            float s = 0.f;
#pragma unroll
            for (int nt = 0; nt < 4; ++nt) {
                float v = acc[mt][nt][rr];
                s = fmaf(v, v, s);
            }
#pragma unroll
            for (int st = 1; st < 16; st <<= 1) s += __shfl_xor(s, st);
            if (lr == 0)
                sblk[wc * 128 + wr * 64 + mt * 16 + quad * 4 + rr] = s;
        }
    __syncthreads();
    if (tid < 128) {
        float* sep = (cbi == 0) ? se0 : se1;
        sep[n0 + tid] = sblk[tid] + sblk[128 + tid];
    }
}

// ---------------------------------------------------------------- K1:
// Fused bf16x2 (3-term) 16x16x32-MFMA GEMM + argmin — session-best
// configuration (R10/R12): R0 body (4 indep acc chains, 120 VGPR,
// 2-phase dbuf) + XCD-affine slab (bid&7) + anti-phase s_sleep for the
// second dispatch sweep. Eight structural variants all pinned the
// barrier-staged family at 51-55% MfmaUtil; this is the best point.
// 1D grid 512: slab = bid&7 (XCD-affine), tokBase = (bid>>3)*128.
__global__ __launch_bounds__(256, 2) void k1_dist_argmin(
    const unsigned short* __restrict__ zh, const unsigned short* __restrict__ zl,
    const unsigned short* __restrict__ eh, const unsigned short* __restrict__ el,
    const float* __restrict__ sz, const float* __restrict__ se0,
    const float* __restrict__ se1, float* __restrict__ pval,
    int* __restrict__ pidx) {
    __shared__ short8 smem[2][2048];   // 2 x 32 KB
    const int tid = threadIdx.x;
    const int w = tid >> 6, lane = tid & 63;
    const int quad = lane >> 4, lr = lane & 15;
    const int bid = blockIdx.x;
    const int slab = bid & 7;              // id%8 == XCD
    const int tokBase = (bid >> 3) * 128;
    const int rowBase = tokBase + w * 32;
    const int slabBase = slab * 2048;

    // anti-phase-lock: offset the second dispatch sweep by ~half a
    // chunk period (55*64 = 3520 cy)
    if (bid & 256) asm volatile("s_sleep 55");

    // A fragments resident for the whole kernel (128 VGPRs)
    short8 Ah[2][8], Al[2][8];
#pragma unroll
    for (int mt = 0; mt < 2; ++mt)
#pragma unroll
        for (int ks = 0; ks < 8; ++ks) {
            size_t o = (size_t)(rowBase + mt * 16 + lr) * 256 + ks * 32 + quad * 8;
            Ah[mt][ks] = *(const short8*)(zh + o);
            Al[mt][ks] = *(const short8*)(zl + o);
        }

    float szr[2][4];
#pragma unroll
    for (int mt = 0; mt < 2; ++mt)
#pragma unroll
        for (int rr = 0; rr < 4; ++rr)
            szr[mt][rr] = sz[rowBase + mt * 16 + quad * 4 + rr];

    float minv[2][4];
    int mini[2][4];
#pragma unroll
    for (int mt = 0; mt < 2; ++mt)
#pragma unroll
        for (int rr = 0; rr < 4; ++rr) {
            minv[mt][rr] = INFINITY;
            mini[mt][rr] = 0;
        }

    // stage chunk `ch` (32 codes x 256 k, hi+lo) into buffer `buf`
    auto stage = [&](int buf, int ch) {
        const int colBase = slabBase + ch * 32;
#pragma unroll
        for (int i = 0; i < 8; ++i) {
            int u = i * 256 + tid;      // 0..2047
            int fmt = u >> 10;          // wave-uniform
            int u1 = u & 1023;
            int col = u1 >> 5, kgs = u1 & 31;
            int kg = kgs ^ col;         // XOR swizzle
            const unsigned short* g =
                (fmt ? el : eh) + (size_t)(colBase + col) * 256 + kg * 8;
            gload_lds16(g, (char*)&smem[0][0] + buf * 32768 +
                               (((size_t)i * 256 + w * 64) << 4));
        }
    };

    stage(0, 0);
    __syncthreads();

    for (int ch = 0; ch < 64; ++ch) {
        const int cur = ch & 1;
        if (ch + 1 < 64) stage(cur ^ 1, ch + 1);  // async prefetch

        // hoist se loads: ~200cy L2 latency hidden under the MFMA burst
        const int colg0 = slabBase + ch * 32 + lr;
        const int colg1 = colg0 + 16;
        const float sec0 = se0[colg0] + se1[colg0];
        const float sec1 = se0[colg1] + se1[colg1];

        f32x4v acc[2][2];
#pragma unroll
        for (int mt = 0; mt < 2; ++mt)
#pragma unroll
            for (int nt = 0; nt < 2; ++nt)
                acc[mt][nt] = (f32x4v){0.f, 0.f, 0.f, 0.f};

#pragma unroll
        for (int ks = 0; ks < 8; ++ks) {
            short8 Bh[2], Bl[2];
#pragma unroll
            for (int nt = 0; nt < 2; ++nt) {
                int col = nt * 16 + lr;
                int kgs = (ks * 4 + quad) ^ col;
                Bh[nt] = smem[cur][col * 32 + kgs];
                Bl[nt] = smem[cur][1024 + col * 32 + kgs];
            }
#pragma unroll
            for (int mt = 0; mt < 2; ++mt)
#pragma unroll
                for (int nt = 0; nt < 2; ++nt) {
                    f32x4v a = acc[mt][nt];
                    a = __builtin_amdgcn_mfma_f32_16x16x32_bf16(Ah[mt][ks], Bh[nt], a, 0, 0, 0);
                    a = __builtin_amdgcn_mfma_f32_16x16x32_bf16(Ah[mt][ks], Bl[nt], a, 0, 0, 0);
                    a = __builtin_amdgcn_mfma_f32_16x16x32_bf16(Al[mt][ks], Bh[nt], a, 0, 0, 0);
                    acc[mt][nt] = a;
                }
        }

        // d = fma(-2, dot, fl(sz+se)) == fl(fl(sz+se) - 2*dot) exactly
        const int colBase = slabBase + ch * 32;
#pragma unroll
        for (int nt = 0; nt < 2; ++nt) {
            const int colg = colBase + nt * 16 + lr;
            const float sec = nt ? sec1 : sec0;
#pragma unroll
            for (int mt = 0; mt < 2; ++mt)
#pragma unroll
                for (int rr = 0; rr < 4; ++rr) {
                    float szse = __fadd_rn(szr[mt][rr], sec);
                    float d = fmaf(-2.0f, acc[mt][nt][rr], szse);
                    if (d < minv[mt][rr]) {   // strict <: first index wins
                        minv[mt][rr] = d;
                        mini[mt][rr] = colg;
                    }
                }
        }
        __syncthreads();   // prefetch landed + cur consumed
    }

    // reduce across the 16 lanes (lr) that share each output row
#pragma unroll
    for (int st = 1; st < 16; st <<= 1) {
#pragma unroll
        for (int mt = 0; mt < 2; ++mt)
#pragma unroll
            for (int rr = 0; rr < 4; ++rr) {
                float ov = __shfl_xor(minv[mt][rr], st);
                int oi = __shfl_xor(mini[mt][rr], st);
                if (ov < minv[mt][rr] ||
                    (ov == minv[mt][rr] && oi < mini[mt][rr])) {
                    minv[mt][rr] = ov;
                    mini[mt][rr] = oi;
                }
            }
    }
    if (lr == 0) {
#pragma unroll
        for (int mt = 0; mt < 2; ++mt)
#pragma unroll
            for (int rr = 0; rr < 4; ++rr) {
                int row = rowBase + mt * 16 + quad * 4 + rr;
                pval[(size_t)row * 8 + slab] = minv[mt][rr];
                pidx[(size_t)row * 8 + slab] = mini[mt][rr];
            }
    }
}

// ---------------------------------------------------------------- K3a:
// per-token: reduce 8 slab partials -> final index; rotation scalars;
// per-block loss partial.
__global__ __launch_bounds__(256) void k3a_token(
    const float* __restrict__ z_flat, const float* __restrict__ emb,
    const float* __restrict__ pval, const int* __restrict__ pidx,
    float* __restrict__ alpha, float* __restrict__ beta,
    int* __restrict__ idxf, float* __restrict__ out,
    float* __restrict__ lpart) {
    __shared__ float red[4];
    const int w = threadIdx.x >> 6, lane = threadIdx.x & 63;
    const int t = blockIdx.x * 4 + w;

    float bv = INFINITY;
    int bi = 0x7fffffff;
    if (lane < 8) {
        bv = pval[(size_t)t * 8 + lane];
        bi = pidx[(size_t)t * 8 + lane];
    }
#pragma unroll
    for (int st = 1; st < 8; st <<= 1) {
        float ov = __shfl_xor(bv, st);
        int oi = __shfl_xor(bi, st);
        if (ov < bv || (ov == bv && oi < bi)) { bv = ov; bi = oi; }
    }
    const int best = __shfl(bi, 0);

    const float4 zv = *(const float4*)(z_flat + (size_t)t * 256 + lane * 4);
    const float4 ev = *(const float4*)(emb + (size_t)best * 256 + lane * 4);
    float szs = zv.x * zv.x + zv.y * zv.y + zv.z * zv.z + zv.w * zv.w;
    float ses = ev.x * ev.x + ev.y * ev.y + ev.z * ev.z + ev.w * ev.w;
    float zes = zv.x * ev.x + zv.y * ev.y + zv.z * ev.z + zv.w * ev.w;
    float dx = zv.x - ev.x, dy = zv.y - ev.y, dz = zv.z - ev.z, dw = zv.w - ev.w;
    float sqs = dx * dx + dy * dy + dz * dz + dw * dw;
#pragma unroll
    for (int m = 1; m < 64; m <<= 1) {
        szs += __shfl_xor(szs, m);
        ses += __shfl_xor(ses, m);
        zes += __shfl_xor(zes, m);
        sqs += __shfl_xor(sqs, m);
    }
    if (lane == 0) {
        float ns = sqrtf(szs), nt = sqrtf(ses);
        float inv_s = 1.0f / (ns + EPSV);
        float inv_t = 1.0f / (nt + EPSV);
        float s2 = szs * inv_s;                      // z . u
        float su = szs * inv_s * inv_s;
        float sq = ses * inv_t * inv_t;
        float uq = zes * inv_s * inv_t;
        float nw = sqrtf(su + sq + 2.0f * uq);
        float inv_w = 1.0f / (nw + EPSV);
        float s1 = (s2 + zes * inv_t) * inv_w;       // z . w_
        float scale = nt * inv_s;
        float a = scale * (1.0f - 2.0f * s1 * inv_w * inv_s);
        float bb = scale * inv_t * 2.0f * (s2 - s1 * inv_w);
        alpha[t] = a;
        beta[t] = bb;
        idxf[t] = best;
        out[2097153 + t] = (float)best;
        red[w] = sqs;
    }
    __syncthreads();
    if (threadIdx.x == 0)
        lpart[blockIdx.x] = red[0] + red[1] + red[2] + red[3];
}

// ---------------------------------------------------------------- K3b:
// z_q = alpha[t]*z + beta[t]*emb[idx[t]]; block 0 also writes the loss.
// 4 elems/thread (same c, tokens t0..t0+3), float4 I/O, 2048 blocks.
__global__ __launch_bounds__(256) void k3b_zq(
    const float* __restrict__ zin, const float* __restrict__ emb,
    const float* __restrict__ alpha, const float* __restrict__ beta,
    const int* __restrict__ idxf, const float* __restrict__ lpart,
    float* __restrict__ out) {
    if (blockIdx.x == 0) {             // ---- loss reduction
        __shared__ float red[4];
        const int tid = threadIdx.x;
        float s = 0.0f;
        for (int i = tid; i < 2048; i += 256) s += lpart[i];
#pragma unroll
        for (int m = 1; m < 64; m <<= 1) s += __shfl_xor(s, m);
        if ((tid & 63) == 0) red[tid >> 6] = s;
        __syncthreads();
        if (tid == 0)
            out[2097152] = 1.25f * (red[0] + red[1] + red[2] + red[3]) *
                           (1.0f / 2097152.0f);
    }
    const int i4 = (blockIdx.x * 256 + threadIdx.x) * 4;
    const int c = (i4 >> 10) & 255;
    const int t0 = ((i4 >> 18) << 10) | (i4 & 1023);   // tokens t0..t0+3
    const float4 zv = *(const float4*)(zin + i4);
    const float4 av = *(const float4*)(alpha + t0);
    const float4 bv = *(const float4*)(beta + t0);
    const int4  iv = *(const int4*)(idxf + t0);
    float4 o;
    o.x = av.x * zv.x + bv.x * emb[(size_t)iv.x * 256 + c];
    o.y = av.y * zv.y + bv.y * emb[(size_t)iv.y * 256 + c];
    o.z = av.z * zv.z + bv.z * emb[(size_t)iv.z * 256 + c];
    o.w = av.w * zv.w + bv.w * emb[(size_t)iv.w * 256 + c];
    *(float4*)(out + i4) = o;
}

// ----------------------------------------------------------------
extern "C" void kernel_launch(void* const* d_in, const int* in_sizes, int n_in,
                              void* d_out, int out_size, void* d_ws,
                              size_t ws_size, hipStream_t stream) {
    (void)in_sizes; (void)n_in; (void)out_size; (void)ws_size;
    const float* zin = (const float*)d_in[0];
    const float* cb  = (const float*)d_in[1];
    const float* Wm  = (const float*)d_in[2];
    float* out = (float*)d_out;
    char* ws = (char*)d_ws;

    float*          z_flat = (float*)(ws + 0);                     //  8 MB
    unsigned short* zh     = (unsigned short*)(ws + 8388608);      //  4 MB
    unsigned short* zl     = (unsigned short*)(ws + 12582912);     //  4 MB
    float*          emb    = (float*)(ws + 16777216);              // 16 MB
    unsigned short* eh     = (unsigned short*)(ws + 33554432);     //  8 MB
    unsigned short* el     = (unsigned short*)(ws + 41943040);     //  8 MB
    float*          sz     = (float*)(ws + 50331648);              // 32 KB
    float*          se0    = (float*)(ws + 50364416);              // 64 KB
    float*          se1    = (float*)(ws + 50429952);              // 64 KB
    float*          pval   = (float*)(ws + 50495488);              // 256 KB
    int*            pidx   = (int*)(ws + 50757632);                // 256 KB
    float*          alpha  = (float*)(ws + 51019776);              // 32 KB
    float*          beta   = (float*)(ws + 51052544);              // 32 KB
    int*            idxf   = (int*)(ws + 51085312);                // 32 KB
    float*          lpart  = (float*)(ws + 51118080);              //  8 KB

    k0c_fz<<<384, 256, 0, stream>>>(cb, Wm, emb, eh, el, se0, se1,
                                    zin, z_flat, zh, zl, sz);
    k1_dist_argmin<<<512, 256, 0, stream>>>(zh, zl, eh, el, sz,
                                            se0, se1, pval, pidx);
    k3a_token<<<2048, 256, 0, stream>>>(z_flat, emb, pval, pidx, alpha, beta,
                                        idxf, out, lpart);
    k3b_zq<<<2048, 256, 0, stream>>>(zin, emb, alpha, beta, idxf, lpart, out);
}

// Round 15
// 282.121 us; speedup vs baseline: 1.0191x; 1.0191x over previous
//
#include <hip/hip_runtime.h>
#include <math.h>

#define EPSV 1e-6f
#define NTOK 8192
#define NE   16384
#define DIM  256

using short8 = __attribute__((ext_vector_type(8))) short;
using f32x4v = __attribute__((ext_vector_type(4))) float;

__device__ __forceinline__ unsigned short f2bf(float v) {
    unsigned int u = __float_as_uint(v);
    u += 0x7fffu + ((u >> 16) & 1u);   // RNE
    return (unsigned short)(u >> 16);
}
__device__ __forceinline__ float bf2f(unsigned short h) {
    return __uint_as_float(((unsigned int)h) << 16);
}

__device__ __forceinline__ void gload_lds16(const void* g, void* s) {
    __builtin_amdgcn_global_load_lds(
        (const __attribute__((address_space(1))) void*)g,
        (__attribute__((address_space(3))) void*)s, 16, 0, 0);
}

// split 8 consecutive fp32 into bf16 hi/lo fragments
__device__ __forceinline__ void split8(const float4 a, const float4 b,
                                       short8& h, short8& l) {
    float f[8] = {a.x, a.y, a.z, a.w, b.x, b.y, b.z, b.w};
#pragma unroll
    for (int j = 0; j < 8; ++j) {
        unsigned short hh = f2bf(f[j]);
        h[j] = (short)hh;
        l[j] = (short)f2bf(f[j] - bf2f(hh));
    }
}

// ---------------------------------------------------------------- fW:
// W (256x256) bf16 hi/lo split. 64 blocks.
__global__ __launch_bounds__(256) void fW_pre(
    const float* __restrict__ Wm, unsigned short* __restrict__ wh,
    unsigned short* __restrict__ wl) {
    const int i = (blockIdx.x * 256 + threadIdx.x) * 4;
    const float4 v = *(const float4*)(Wm + i);
    float f[4] = {v.x, v.y, v.z, v.w};
#pragma unroll
    for (int j = 0; j < 4; ++j) {
        unsigned short h = f2bf(f[j]);
        wh[i + j] = h;
        wl[i + j] = f2bf(f[j] - bf2f(h));
    }
}

// ---------------------------------------------------------------- K0c+fZ:
// blocks [0,256): emb = codebook @ W.T via 4-term bf16x2 MFMA + bf16
//   split + per-c-tile se partials (nb=bid&127 -> n0, cb=bid>>7 -> c0).
// blocks [256,384): z transpose + bf16 split + per-token sz (fp64).
__global__ __launch_bounds__(256, 2) void k0c_fz(
    const float* __restrict__ cb, const unsigned short* __restrict__ wh,
    const unsigned short* __restrict__ wl, float* __restrict__ emb,
    unsigned short* __restrict__ eh, unsigned short* __restrict__ el,
    float* __restrict__ se0, float* __restrict__ se1,
    const float* __restrict__ zin, float* __restrict__ z_flat,
    unsigned short* __restrict__ zh, unsigned short* __restrict__ zl,
    float* __restrict__ sz) {
    __shared__ char smemU[65536];
    const int bid = blockIdx.x;
    const int tid = threadIdx.x;

    if (bid >= 256) {                  // ---- fZ: z transpose + split + sz
        float (*tile)[65] = (float(*)[65])smemU;   // 16.6 KB of smemU
        const int zbid = bid - 256;
        const int yx0 = (zbid & 15) * 64, b = zbid >> 4;
        const int sub = tid >> 6, ln = tid & 63;
        double dacc[16];
#pragma unroll
        for (int j = 0; j < 16; ++j) dacc[j] = 0.0;

        for (int cc = 0; cc < 4; ++cc) {
            const int c0 = cc * 64;
            __syncthreads();
#pragma unroll
            for (int j = 0; j < 16; ++j) {
                int cl = j * 4 + sub;
                tile[cl][ln] = zin[((size_t)(b * 256 + c0 + cl) << 10) + yx0 + ln];
            }
            __syncthreads();
#pragma unroll
            for (int j = 0; j < 16; ++j) {
                int tl = j * 4 + sub;
                float v = tile[ln][tl];
                size_t o = (size_t)(b * 1024 + yx0 + tl) * 256 + c0 + ln;
                z_flat[o] = v;
                unsigned short h = f2bf(v);
                zh[o] = h;
                zl[o] = f2bf(v - bf2f(h));
                dacc[j] += (double)v * v;
            }
        }
#pragma unroll
        for (int j = 0; j < 16; ++j) {
            double s = dacc[j];
#pragma unroll
            for (int m = 1; m < 64; m <<= 1) s += __shfl_xor(s, m);
            if (ln == 0) sz[b * 1024 + yx0 + j * 4 + sub] = (float)s;
        }
        return;
    }

    // ---- k0c: emb GEMM
    char* smemC = smemU;
    const int w = tid >> 6, lane = tid & 63;
    const int quad = lane >> 4, lr = lane & 15;
    const int wr = w & 1, wc = w >> 1;
    const int nb = bid & 127, cbi = bid >> 7;
    const int n0 = nb * 128, c0 = cbi * 128;

    f32x4v acc[4][4];
#pragma unroll
    for (int mt = 0; mt < 4; ++mt)
#pragma unroll
        for (int nt = 0; nt < 4; ++nt)
            acc[mt][nt] = (f32x4v){0.f, 0.f, 0.f, 0.f};

    for (int kc = 0; kc < 4; ++kc) {
        __syncthreads();
#pragma unroll
        for (int i = 0; i < 16; ++i) {
            int s = i * 4 + w;           // wave-uniform segment 0..63
            int u = s * 64 + lane;       // global unit 0..4095
            const void* g;
            if (s < 32) {                // cbS: [kg(16)][row(128)] fp32x4
                int kg = u >> 7, row = u & 127;
                g = cb + (size_t)(n0 + row) * 256 + kc * 64 + kg * 4;
            } else if (s < 48) {         // whS: [kg(8)][row(128)] bf16x8
                int u1 = u - 2048;
                int kg = u1 >> 7, row = u1 & 127;
                g = wh + (size_t)(c0 + row) * 256 + kc * 64 + kg * 8;
            } else {                     // wlS
                int u2 = u - 3072;
                int kg = u2 >> 7, row = u2 & 127;
                g = wl + (size_t)(c0 + row) * 256 + kc * 64 + kg * 8;
            }
            gload_lds16(g, smemC + ((size_t)u << 4));
        }
        __syncthreads();
#pragma unroll
        for (int ks = 0; ks < 2; ++ks) {
            short8 Ah[4], Al[4], Bh[4], Bl[4];
#pragma unroll
            for (int mt = 0; mt < 4; ++mt) {
                int m = wr * 64 + mt * 16 + lr;
                int kg2 = ks * 8 + quad * 2;
                float4 f0 = *(const float4*)(smemC + (((size_t)kg2 * 128 + m) << 4));
                float4 f1 = *(const float4*)(smemC + ((((size_t)kg2 + 1) * 128 + m) << 4));
                split8(f0, f1, Ah[mt], Al[mt]);
            }
#pragma unroll
            for (int nt = 0; nt < 4; ++nt) {
                int n = wc * 64 + nt * 16 + lr;
                int ku = (ks * 4 + quad) * 128 + n;
                Bh[nt] = *(const short8*)(smemC + (((size_t)2048 + ku) << 4));
                Bl[nt] = *(const short8*)(smemC + (((size_t)3072 + ku) << 4));
            }
#pragma unroll
            for (int mt = 0; mt < 4; ++mt)
#pragma unroll
                for (int nt = 0; nt < 4; ++nt) {
                    f32x4v a = acc[mt][nt];
                    a = __builtin_amdgcn_mfma_f32_16x16x32_bf16(Ah[mt], Bh[nt], a, 0, 0, 0);
                    a = __builtin_amdgcn_mfma_f32_16x16x32_bf16(Ah[mt], Bl[nt], a, 0, 0, 0);
                    a = __builtin_amdgcn_mfma_f32_16x16x32_bf16(Al[mt], Bh[nt], a, 0, 0, 0);
                    a = __builtin_amdgcn_mfma_f32_16x16x32_bf16(Al[mt], Bl[nt], a, 0, 0, 0);
                    acc[mt][nt] = a;
                }
        }
    }
#pragma unroll
    for (int mt = 0; mt < 4; ++mt)
#pragma unroll
        for (int rr = 0; rr < 4; ++rr) {
            int row = n0 + wr * 64 + mt * 16 + quad * 4 + rr;
#pragma unroll
            for (int nt = 0; nt < 4; ++nt) {
                int col = c0 + wc * 64 + nt * 16 + lr;
                size_t o = (size_t)row * 256 + col;
                float v = acc[mt][nt][rr];
                emb[o] = v;
                unsigned short h = f2bf(v);
                eh[o] = h;
                el[o] = f2bf(v - bf2f(h));
            }
        }
    // ---- se partial over this block's 128 cols
    __syncthreads();
    float* sblk = (float*)smemC;       // [2][128]
#pragma unroll
    for (int mt = 0; mt < 4; ++mt)
#pragma unroll
        for (int rr = 0; rr < 4; ++rr) {
            float s = 0.f;
#pragma unroll
            for (int nt = 0; nt < 4; ++nt) {
                float v = acc[mt][nt][rr];
                s = fmaf(v, v, s);
            }
#pragma unroll
            for (int st = 1; st < 16; st <<= 1) s += __shfl_xor(s, st);
            if (lr == 0)
                sblk[wc * 128 + wr * 64 + mt * 16 + quad * 4 + rr] = s;
        }
    __syncthreads();
    if (tid < 128) {
        float* sep = (cbi == 0) ? se0 : se1;
        sep[n0 + tid] = sblk[tid] + sblk[128 + tid];
    }
}

// ---------------------------------------------------------------- K1:
// Fused bf16x2 (3-term) 16x16x32-MFMA GEMM + argmin — session-best
// configuration (R10/R12): R0 body (4 indep acc chains, 120 VGPR,
// 2-phase dbuf) + XCD-affine slab (bid&7) + anti-phase s_sleep for the
// second dispatch sweep. Nine structural variants all pinned the
// barrier-staged family at 51-55% MfmaUtil; this is the best point.
// 1D grid 512: slab = bid&7 (XCD-affine), tokBase = (bid>>3)*128.
__global__ __launch_bounds__(256, 2) void k1_dist_argmin(
    const unsigned short* __restrict__ zh, const unsigned short* __restrict__ zl,
    const unsigned short* __restrict__ eh, const unsigned short* __restrict__ el,
    const float* __restrict__ sz, const float* __restrict__ se0,
    const float* __restrict__ se1, float* __restrict__ pval,
    int* __restrict__ pidx) {
    __shared__ short8 smem[2][2048];   // 2 x 32 KB
    const int tid = threadIdx.x;
    const int w = tid >> 6, lane = tid & 63;
    const int quad = lane >> 4, lr = lane & 15;
    const int bid = blockIdx.x;
    const int slab = bid & 7;              // id%8 == XCD
    const int tokBase = (bid >> 3) * 128;
    const int rowBase = tokBase + w * 32;
    const int slabBase = slab * 2048;

    // anti-phase-lock: offset the second dispatch sweep by ~half a
    // chunk period (55*64 = 3520 cy)
    if (bid & 256) asm volatile("s_sleep 55");

    // A fragments resident for the whole kernel (128 VGPRs)
    short8 Ah[2][8], Al[2][8];
#pragma unroll
    for (int mt = 0; mt < 2; ++mt)
#pragma unroll
        for (int ks = 0; ks < 8; ++ks) {
            size_t o = (size_t)(rowBase + mt * 16 + lr) * 256 + ks * 32 + quad * 8;
            Ah[mt][ks] = *(const short8*)(zh + o);
            Al[mt][ks] = *(const short8*)(zl + o);
        }

    float szr[2][4];
#pragma unroll
    for (int mt = 0; mt < 2; ++mt)
#pragma unroll
        for (int rr = 0; rr < 4; ++rr)
            szr[mt][rr] = sz[rowBase + mt * 16 + quad * 4 + rr];

    float minv[2][4];
    int mini[2][4];
#pragma unroll
    for (int mt = 0; mt < 2; ++mt)
#pragma unroll
        for (int rr = 0; rr < 4; ++rr) {
            minv[mt][rr] = INFINITY;
            mini[mt][rr] = 0;
        }

    // stage chunk `ch` (32 codes x 256 k, hi+lo) into buffer `buf`
    auto stage = [&](int buf, int ch) {
        const int colBase = slabBase + ch * 32;
#pragma unroll
        for (int i = 0; i < 8; ++i) {
            int u = i * 256 + tid;      // 0..2047
            int fmt = u >> 10;          // wave-uniform
            int u1 = u & 1023;
            int col = u1 >> 5, kgs = u1 & 31;
            int kg = kgs ^ col;         // XOR swizzle
            const unsigned short* g =
                (fmt ? el : eh) + (size_t)(colBase + col) * 256 + kg * 8;
            gload_lds16(g, (char*)&smem[0][0] + buf * 32768 +
                               (((size_t)i * 256 + w * 64) << 4));
        }
    };

    stage(0, 0);
    __syncthreads();

    for (int ch = 0; ch < 64; ++ch) {
        const int cur = ch & 1;
        if (ch + 1 < 64) stage(cur ^ 1, ch + 1);  // async prefetch

        // hoist se loads: ~200cy L2 latency hidden under the MFMA burst
        const int colg0 = slabBase + ch * 32 + lr;
        const int colg1 = colg0 + 16;
        const float sec0 = se0[colg0] + se1[colg0];
        const float sec1 = se0[colg1] + se1[colg1];

        f32x4v acc[2][2];
#pragma unroll
        for (int mt = 0; mt < 2; ++mt)
#pragma unroll
            for (int nt = 0; nt < 2; ++nt)
                acc[mt][nt] = (f32x4v){0.f, 0.f, 0.f, 0.f};

#pragma unroll
        for (int ks = 0; ks < 8; ++ks) {
            short8 Bh[2], Bl[2];
#pragma unroll
            for (int nt = 0; nt < 2; ++nt) {
                int col = nt * 16 + lr;
                int kgs = (ks * 4 + quad) ^ col;
                Bh[nt] = smem[cur][col * 32 + kgs];
                Bl[nt] = smem[cur][1024 + col * 32 + kgs];
            }
#pragma unroll
            for (int mt = 0; mt < 2; ++mt)
#pragma unroll
                for (int nt = 0; nt < 2; ++nt) {
                    f32x4v a = acc[mt][nt];
                    a = __builtin_amdgcn_mfma_f32_16x16x32_bf16(Ah[mt][ks], Bh[nt], a, 0, 0, 0);
                    a = __builtin_amdgcn_mfma_f32_16x16x32_bf16(Ah[mt][ks], Bl[nt], a, 0, 0, 0);
                    a = __builtin_amdgcn_mfma_f32_16x16x32_bf16(Al[mt][ks], Bh[nt], a, 0, 0, 0);
                    acc[mt][nt] = a;
                }
        }

        // d = fma(-2, dot, fl(sz+se)) == fl(fl(sz+se) - 2*dot) exactly
        const int colBase = slabBase + ch * 32;
#pragma unroll
        for (int nt = 0; nt < 2; ++nt) {
            const int colg = colBase + nt * 16 + lr;
            const float sec = nt ? sec1 : sec0;
#pragma unroll
            for (int mt = 0; mt < 2; ++mt)
#pragma unroll
                for (int rr = 0; rr < 4; ++rr) {
                    float szse = __fadd_rn(szr[mt][rr], sec);
                    float d = fmaf(-2.0f, acc[mt][nt][rr], szse);
                    if (d < minv[mt][rr]) {   // strict <: first index wins
                        minv[mt][rr] = d;
                        mini[mt][rr] = colg;
                    }
                }
        }
        __syncthreads();   // prefetch landed + cur consumed
    }

    // reduce across the 16 lanes (lr) that share each output row
#pragma unroll
    for (int st = 1; st < 16; st <<= 1) {
#pragma unroll
        for (int mt = 0; mt < 2; ++mt)
#pragma unroll
            for (int rr = 0; rr < 4; ++rr) {
                float ov = __shfl_xor(minv[mt][rr], st);
                int oi = __shfl_xor(mini[mt][rr], st);
                if (ov < minv[mt][rr] ||
                    (ov == minv[mt][rr] && oi < mini[mt][rr])) {
                    minv[mt][rr] = ov;
                    mini[mt][rr] = oi;
                }
            }
    }
    if (lr == 0) {
#pragma unroll
        for (int mt = 0; mt < 2; ++mt)
#pragma unroll
            for (int rr = 0; rr < 4; ++rr) {
                int row = rowBase + mt * 16 + quad * 4 + rr;
                pval[(size_t)row * 8 + slab] = minv[mt][rr];
                pidx[(size_t)row * 8 + slab] = mini[mt][rr];
            }
    }
}

// ---------------------------------------------------------------- K3a:
// per-token: reduce 8 slab partials -> final index; rotation scalars;
// per-block loss partial.
__global__ __launch_bounds__(256) void k3a_token(
    const float* __restrict__ z_flat, const float* __restrict__ emb,
    const float* __restrict__ pval, const int* __restrict__ pidx,
    float* __restrict__ alpha, float* __restrict__ beta,
    int* __restrict__ idxf, float* __restrict__ out,
    float* __restrict__ lpart) {
    __shared__ float red[4];
    const int w = threadIdx.x >> 6, lane = threadIdx.x & 63;
    const int t = blockIdx.x * 4 + w;

    float bv = INFINITY;
    int bi = 0x7fffffff;
    if (lane < 8) {
        bv = pval[(size_t)t * 8 + lane];
        bi = pidx[(size_t)t * 8 + lane];
    }
#pragma unroll
    for (int st = 1; st < 8; st <<= 1) {
        float ov = __shfl_xor(bv, st);
        int oi = __shfl_xor(bi, st);
        if (ov < bv || (ov == bv && oi < bi)) { bv = ov; bi = oi; }
    }
    const int best = __shfl(bi, 0);

    const float4 zv = *(const float4*)(z_flat + (size_t)t * 256 + lane * 4);
    const float4 ev = *(const float4*)(emb + (size_t)best * 256 + lane * 4);
    float szs = zv.x * zv.x + zv.y * zv.y + zv.z * zv.z + zv.w * zv.w;
    float ses = ev.x * ev.x + ev.y * ev.y + ev.z * ev.z + ev.w * ev.w;
    float zes = zv.x * ev.x + zv.y * ev.y + zv.z * ev.z + zv.w * ev.w;
    float dx = zv.x - ev.x, dy = zv.y - ev.y, dz = zv.z - ev.z, dw = zv.w - ev.w;
    float sqs = dx * dx + dy * dy + dz * dz + dw * dw;
#pragma unroll
    for (int m = 1; m < 64; m <<= 1) {
        szs += __shfl_xor(szs, m);
        ses += __shfl_xor(ses, m);
        zes += __shfl_xor(zes, m);
        sqs += __shfl_xor(sqs, m);
    }
    if (lane == 0) {
        float ns = sqrtf(szs), nt = sqrtf(ses);
        float inv_s = 1.0f / (ns + EPSV);
        float inv_t = 1.0f / (nt + EPSV);
        float s2 = szs * inv_s;                      // z . u
        float su = szs * inv_s * inv_s;
        float sq = ses * inv_t * inv_t;
        float uq = zes * inv_s * inv_t;
        float nw = sqrtf(su + sq + 2.0f * uq);
        float inv_w = 1.0f / (nw + EPSV);
        float s1 = (s2 + zes * inv_t) * inv_w;       // z . w_
        float scale = nt * inv_s;
        float a = scale * (1.0f - 2.0f * s1 * inv_w * inv_s);
        float bb = scale * inv_t * 2.0f * (s2 - s1 * inv_w);
        alpha[t] = a;
        beta[t] = bb;
        idxf[t] = best;
        out[2097153 + t] = (float)best;
        red[w] = sqs;
    }
    __syncthreads();
    if (threadIdx.x == 0)
        lpart[blockIdx.x] = red[0] + red[1] + red[2] + red[3];
}

// ---------------------------------------------------------------- K3b:
// z_q = alpha[t]*z + beta[t]*emb[idx[t]]; block 0 also writes the loss.
// 4 elems/thread (same c, tokens t0..t0+3), float4 I/O, 2048 blocks.
__global__ __launch_bounds__(256) void k3b_zq(
    const float* __restrict__ zin, const float* __restrict__ emb,
    const float* __restrict__ alpha, const float* __restrict__ beta,
    const int* __restrict__ idxf, const float* __restrict__ lpart,
    float* __restrict__ out) {
    if (blockIdx.x == 0) {             // ---- loss reduction
        __shared__ float red[4];
        const int tid = threadIdx.x;
        float s = 0.0f;
        for (int i = tid; i < 2048; i += 256) s += lpart[i];
#pragma unroll
        for (int m = 1; m < 64; m <<= 1) s += __shfl_xor(s, m);
        if ((tid & 63) == 0) red[tid >> 6] = s;
        __syncthreads();
        if (tid == 0)
            out[2097152] = 1.25f * (red[0] + red[1] + red[2] + red[3]) *
                           (1.0f / 2097152.0f);
    }
    const int i4 = (blockIdx.x * 256 + threadIdx.x) * 4;
    const int c = (i4 >> 10) & 255;
    const int t0 = ((i4 >> 18) << 10) | (i4 & 1023);   // tokens t0..t0+3
    const float4 zv = *(const float4*)(zin + i4);
    const float4 av = *(const float4*)(alpha + t0);
    const float4 bv = *(const float4*)(beta + t0);
    const int4  iv = *(const int4*)(idxf + t0);
    float4 o;
    o.x = av.x * zv.x + bv.x * emb[(size_t)iv.x * 256 + c];
    o.y = av.y * zv.y + bv.y * emb[(size_t)iv.y * 256 + c];
    o.z = av.z * zv.z + bv.z * emb[(size_t)iv.z * 256 + c];
    o.w = av.w * zv.w + bv.w * emb[(size_t)iv.w * 256 + c];
    *(float4*)(out + i4) = o;
}

// ----------------------------------------------------------------
extern "C" void kernel_launch(void* const* d_in, const int* in_sizes, int n_in,
                              void* d_out, int out_size, void* d_ws,
                              size_t ws_size, hipStream_t stream) {
    (void)in_sizes; (void)n_in; (void)out_size; (void)ws_size;
    const float* zin = (const float*)d_in[0];
    const float* cb  = (const float*)d_in[1];
    const float* Wm  = (const float*)d_in[2];
    float* out = (float*)d_out;
    char* ws = (char*)d_ws;

    float*          z_flat = (float*)(ws + 0);                     //  8 MB
    unsigned short* zh     = (unsigned short*)(ws + 8388608);      //  4 MB
    unsigned short* zl     = (unsigned short*)(ws + 12582912);     //  4 MB
    float*          emb    = (float*)(ws + 16777216);              // 16 MB
    unsigned short* eh     = (unsigned short*)(ws + 33554432);     //  8 MB
    unsigned short* el     = (unsigned short*)(ws + 41943040);     //  8 MB
    float*          sz     = (float*)(ws + 50331648);              // 32 KB
    float*          se0    = (float*)(ws + 50364416);              // 64 KB
    float*          se1    = (float*)(ws + 50429952);              // 64 KB
    float*          pval   = (float*)(ws + 50495488);              // 256 KB
    int*            pidx   = (int*)(ws + 50757632);                // 256 KB
    float*          alpha  = (float*)(ws + 51019776);              // 32 KB
    float*          beta   = (float*)(ws + 51052544);              // 32 KB
    int*            idxf   = (int*)(ws + 51085312);                // 32 KB
    float*          lpart  = (float*)(ws + 51118080);              //  8 KB
    unsigned short* wh     = (unsigned short*)(ws + 51126272);     // 128 KB
    unsigned short* wl     = (unsigned short*)(ws + 51257344);     // 128 KB

    fW_pre<<<64, 256, 0, stream>>>(Wm, wh, wl);
    k0c_fz<<<384, 256, 0, stream>>>(cb, wh, wl, emb, eh, el, se0, se1,
                                    zin, z_flat, zh, zl, sz);
    k1_dist_argmin<<<512, 256, 0, stream>>>(zh, zl, eh, el, sz,
                                            se0, se1, pval, pidx);
    k3a_token<<<2048, 256, 0, stream>>>(z_flat, emb, pval, pidx, alpha, beta,
                                        idxf, out, lpart);
    k3b_zq<<<2048, 256, 0, stream>>>(zin, emb, alpha, beta, idxf, lpart, out);
}

// Round 16
// 277.254 us; speedup vs baseline: 1.0370x; 1.0176x over previous
//
#include <hip/hip_runtime.h>
#include <math.h>

#define EPSV 1e-6f
#define NTOK 8192
#define NE   16384
#define DIM  256

using short8 = __attribute__((ext_vector_type(8))) short;
using f32x4v = __attribute__((ext_vector_type(4))) float;

__device__ __forceinline__ unsigned short f2bf(float v) {
    unsigned int u = __float_as_uint(v);
    u += 0x7fffu + ((u >> 16) & 1u);   // RNE
    return (unsigned short)(u >> 16);
}
__device__ __forceinline__ float bf2f(unsigned short h) {
    return __uint_as_float(((unsigned int)h) << 16);
}

__device__ __forceinline__ void gload_lds16(const void* g, void* s) {
    __builtin_amdgcn_global_load_lds(
        (const __attribute__((address_space(1))) void*)g,
        (__attribute__((address_space(3))) void*)s, 16, 0, 0);
}

// split 8 consecutive fp32 into bf16 hi/lo fragments
__device__ __forceinline__ void split8(const float4 a, const float4 b,
                                       short8& h, short8& l) {
    float f[8] = {a.x, a.y, a.z, a.w, b.x, b.y, b.z, b.w};
#pragma unroll
    for (int j = 0; j < 8; ++j) {
        unsigned short hh = f2bf(f[j]);
        h[j] = (short)hh;
        l[j] = (short)f2bf(f[j] - bf2f(hh));
    }
}

// ---------------------------------------------------------------- fW:
// W (256x256) bf16 hi/lo split. 64 blocks.
__global__ __launch_bounds__(256) void fW_pre(
    const float* __restrict__ Wm, unsigned short* __restrict__ wh,
    unsigned short* __restrict__ wl) {
    const int i = (blockIdx.x * 256 + threadIdx.x) * 4;
    const float4 v = *(const float4*)(Wm + i);
    float f[4] = {v.x, v.y, v.z, v.w};
#pragma unroll
    for (int j = 0; j < 4; ++j) {
        unsigned short h = f2bf(f[j]);
        wh[i + j] = h;
        wl[i + j] = f2bf(f[j] - bf2f(h));
    }
}

// ---------------------------------------------------------------- K0c+fZ:
// blocks [0,256): emb = codebook @ W.T via 4-term bf16x2 MFMA + bf16
//   split + per-c-tile se partials (nb=bid&127 -> n0, cb=bid>>7 -> c0).
// blocks [256,384): z transpose + bf16 split + per-token sz (fp64).
__global__ __launch_bounds__(256, 2) void k0c_fz(
    const float* __restrict__ cb, const unsigned short* __restrict__ wh,
    const unsigned short* __restrict__ wl, float* __restrict__ emb,
    unsigned short* __restrict__ eh, unsigned short* __restrict__ el,
    float* __restrict__ se0, float* __restrict__ se1,
    const float* __restrict__ zin, float* __restrict__ z_flat,
    unsigned short* __restrict__ zh, unsigned short* __restrict__ zl,
    float* __restrict__ sz) {
    __shared__ char smemU[65536];
    const int bid = blockIdx.x;
    const int tid = threadIdx.x;

    if (bid >= 256) {                  // ---- fZ: z transpose + split + sz
        float (*tile)[65] = (float(*)[65])smemU;   // 16.6 KB of smemU
        const int zbid = bid - 256;
        const int yx0 = (zbid & 15) * 64, b = zbid >> 4;
        const int sub = tid >> 6, ln = tid & 63;
        double dacc[16];
#pragma unroll
        for (int j = 0; j < 16; ++j) dacc[j] = 0.0;

        for (int cc = 0; cc < 4; ++cc) {
            const int c0 = cc * 64;
            __syncthreads();
#pragma unroll
            for (int j = 0; j < 16; ++j) {
                int cl = j * 4 + sub;
                tile[cl][ln] = zin[((size_t)(b * 256 + c0 + cl) << 10) + yx0 + ln];
            }
            __syncthreads();
#pragma unroll
            for (int j = 0; j < 16; ++j) {
                int tl = j * 4 + sub;
                float v = tile[ln][tl];
                size_t o = (size_t)(b * 1024 + yx0 + tl) * 256 + c0 + ln;
                z_flat[o] = v;
                unsigned short h = f2bf(v);
                zh[o] = h;
                zl[o] = f2bf(v - bf2f(h));
                dacc[j] += (double)v * v;
            }
        }
#pragma unroll
        for (int j = 0; j < 16; ++j) {
            double s = dacc[j];
#pragma unroll
            for (int m = 1; m < 64; m <<= 1) s += __shfl_xor(s, m);
            if (ln == 0) sz[b * 1024 + yx0 + j * 4 + sub] = (float)s;
        }
        return;
    }

    // ---- k0c: emb GEMM
    char* smemC = smemU;
    const int w = tid >> 6, lane = tid & 63;
    const int quad = lane >> 4, lr = lane & 15;
    const int wr = w & 1, wc = w >> 1;
    const int nb = bid & 127, cbi = bid >> 7;
    const int n0 = nb * 128, c0 = cbi * 128;

    f32x4v acc[4][4];
#pragma unroll
    for (int mt = 0; mt < 4; ++mt)
#pragma unroll
        for (int nt = 0; nt < 4; ++nt)
            acc[mt][nt] = (f32x4v){0.f, 0.f, 0.f, 0.f};

    for (int kc = 0; kc < 4; ++kc) {
        __syncthreads();
#pragma unroll
        for (int i = 0; i < 16; ++i) {
            int s = i * 4 + w;           // wave-uniform segment 0..63
            int u = s * 64 + lane;       // global unit 0..4095
            const void* g;
            if (s < 32) {                // cbS: [kg(16)][row(128)] fp32x4
                int kg = u >> 7, row = u & 127;
                g = cb + (size_t)(n0 + row) * 256 + kc * 64 + kg * 4;
            } else if (s < 48) {         // whS: [kg(8)][row(128)] bf16x8
                int u1 = u - 2048;
                int kg = u1 >> 7, row = u1 & 127;
                g = wh + (size_t)(c0 + row) * 256 + kc * 64 + kg * 8;
            } else {                     // wlS
                int u2 = u - 3072;
                int kg = u2 >> 7, row = u2 & 127;
                g = wl + (size_t)(c0 + row) * 256 + kc * 64 + kg * 8;
            }
            gload_lds16(g, smemC + ((size_t)u << 4));
        }
        __syncthreads();
#pragma unroll
        for (int ks = 0; ks < 2; ++ks) {
            short8 Ah[4], Al[4], Bh[4], Bl[4];
#pragma unroll
            for (int mt = 0; mt < 4; ++mt) {
                int m = wr * 64 + mt * 16 + lr;
                int kg2 = ks * 8 + quad * 2;
                float4 f0 = *(const float4*)(smemC + (((size_t)kg2 * 128 + m) << 4));
                float4 f1 = *(const float4*)(smemC + ((((size_t)kg2 + 1) * 128 + m) << 4));
                split8(f0, f1, Ah[mt], Al[mt]);
            }
#pragma unroll
            for (int nt = 0; nt < 4; ++nt) {
                int n = wc * 64 + nt * 16 + lr;
                int ku = (ks * 4 + quad) * 128 + n;
                Bh[nt] = *(const short8*)(smemC + (((size_t)2048 + ku) << 4));
                Bl[nt] = *(const short8*)(smemC + (((size_t)3072 + ku) << 4));
            }
#pragma unroll
            for (int mt = 0; mt < 4; ++mt)
#pragma unroll
                for (int nt = 0; nt < 4; ++nt) {
                    f32x4v a = acc[mt][nt];
                    a = __builtin_amdgcn_mfma_f32_16x16x32_bf16(Ah[mt], Bh[nt], a, 0, 0, 0);
                    a = __builtin_amdgcn_mfma_f32_16x16x32_bf16(Ah[mt], Bl[nt], a, 0, 0, 0);
                    a = __builtin_amdgcn_mfma_f32_16x16x32_bf16(Al[mt], Bh[nt], a, 0, 0, 0);
                    a = __builtin_amdgcn_mfma_f32_16x16x32_bf16(Al[mt], Bl[nt], a, 0, 0, 0);
                    acc[mt][nt] = a;
                }
        }
    }
#pragma unroll
    for (int mt = 0; mt < 4; ++mt)
#pragma unroll
        for (int rr = 0; rr < 4; ++rr) {
            int row = n0 + wr * 64 + mt * 16 + quad * 4 + rr;
#pragma unroll
            for (int nt = 0; nt < 4; ++nt) {
                int col = c0 + wc * 64 + nt * 16 + lr;
                size_t o = (size_t)row * 256 + col;
                float v = acc[mt][nt][rr];
                emb[o] = v;
                unsigned short h = f2bf(v);
                eh[o] = h;
                el[o] = f2bf(v - bf2f(h));
            }
        }
    // ---- se partial over this block's 128 cols
    __syncthreads();
    float* sblk = (float*)smemC;       // [2][128]
#pragma unroll
    for (int mt = 0; mt < 4; ++mt)
#pragma unroll
        for (int rr = 0; rr < 4; ++rr) {
            float s = 0.f;
#pragma unroll
            for (int nt = 0; nt < 4; ++nt) {
                float v = acc[mt][nt][rr];
                s = fmaf(v, v, s);
            }
#pragma unroll
            for (int st = 1; st < 16; st <<= 1) s += __shfl_xor(s, st);
            if (lr == 0)
                sblk[wc * 128 + wr * 64 + mt * 16 + quad * 4 + rr] = s;
        }
    __syncthreads();
    if (tid < 128) {
        float* sep = (cbi == 0) ? se0 : se1;
        sep[n0 + tid] = sblk[tid] + sblk[128 + tid];
    }
}

// ---------------------------------------------------------------- K1:
// Fused bf16x2 (3-term) 16x16x32-MFMA GEMM + argmin — session-best
// body (R10/R12/R14) + R15 delta: STAGE-ADDRESS STRENGTH REDUCTION.
// The stage lambda previously recomputed col/kg/64-bit address for all
// 8 loads every chunk (~64 VALU/thread/chunk — ~1/3 of VALUBusy=30%).
// Now: 8 per-thread element offsets precomputed once (base buffer is
// compile-time: fmt = i>=4), per chunk addr = base + goff[i] + ch*8192.
// Bit-identical addresses, same LDS dests + swizzle. +8 VGPR (goff).
// 1D grid 512: slab = bid&7 (XCD-affine), anti-phase s_sleep kept.
__global__ __launch_bounds__(256, 2) void k1_dist_argmin(
    const unsigned short* __restrict__ zh, const unsigned short* __restrict__ zl,
    const unsigned short* __restrict__ eh, const unsigned short* __restrict__ el,
    const float* __restrict__ sz, const float* __restrict__ se0,
    const float* __restrict__ se1, float* __restrict__ pval,
    int* __restrict__ pidx) {
    __shared__ short8 smem[2][2048];   // 2 x 32 KB
    const int tid = threadIdx.x;
    const int w = tid >> 6, lane = tid & 63;
    const int quad = lane >> 4, lr = lane & 15;
    const int bid = blockIdx.x;
    const int slab = bid & 7;              // id%8 == XCD
    const int tokBase = (bid >> 3) * 128;
    const int rowBase = tokBase + w * 32;
    const int slabBase = slab * 2048;

    // anti-phase-lock: offset the second dispatch sweep by ~half a
    // chunk period (55*64 = 3520 cy)
    if (bid & 256) asm volatile("s_sleep 55");

    // A fragments resident for the whole kernel (128 VGPRs)
    short8 Ah[2][8], Al[2][8];
#pragma unroll
    for (int mt = 0; mt < 2; ++mt)
#pragma unroll
        for (int ks = 0; ks < 8; ++ks) {
            size_t o = (size_t)(rowBase + mt * 16 + lr) * 256 + ks * 32 + quad * 8;
            Ah[mt][ks] = *(const short8*)(zh + o);
            Al[mt][ks] = *(const short8*)(zl + o);
        }

    float szr[2][4];
#pragma unroll
    for (int mt = 0; mt < 2; ++mt)
#pragma unroll
        for (int rr = 0; rr < 4; ++rr)
            szr[mt][rr] = sz[rowBase + mt * 16 + quad * 4 + rr];

    float minv[2][4];
    int mini[2][4];
#pragma unroll
    for (int mt = 0; mt < 2; ++mt)
#pragma unroll
        for (int rr = 0; rr < 4; ++rr) {
            minv[mt][rr] = INFINITY;
            mini[mt][rr] = 0;
        }

    // strength-reduced staging: per-thread element offsets, computed once.
    // load i reads (fmt?el:eh) + (slabBase+col)*256 + kg*8 + ch*8192,
    // with u = i*256+tid, fmt = u>>10 = (i>=4), col=(u&1023)>>5,
    // kg = (u&31) ^ col (XOR swizzle, write side).
    unsigned int goff[8];
#pragma unroll
    for (int i = 0; i < 8; ++i) {
        int u = i * 256 + tid;
        int u1 = u & 1023;
        int col = u1 >> 5, kgs = u1 & 31;
        int kg = kgs ^ col;
        goff[i] = (unsigned int)((slabBase + col) * 256 + kg * 8);
    }

    // stage chunk `ch` (32 codes x 256 k, hi+lo) into buffer `buf`
    auto stage = [&](int buf, int ch) {
        const unsigned int choff = (unsigned int)ch << 13;   // ch * 8192
#pragma unroll
        for (int i = 0; i < 8; ++i) {
            const unsigned short* g =
                (i < 4 ? eh : el) + goff[i] + choff;
            gload_lds16(g, (char*)&smem[0][0] + buf * 32768 +
                               (((size_t)i * 256 + w * 64) << 4));
        }
    };

    stage(0, 0);
    __syncthreads();

    for (int ch = 0; ch < 64; ++ch) {
        const int cur = ch & 1;
        if (ch + 1 < 64) stage(cur ^ 1, ch + 1);  // async prefetch

        // hoist se loads: ~200cy L2 latency hidden under the MFMA burst
        const int colg0 = slabBase + ch * 32 + lr;
        const int colg1 = colg0 + 16;
        const float sec0 = se0[colg0] + se1[colg0];
        const float sec1 = se0[colg1] + se1[colg1];

        f32x4v acc[2][2];
#pragma unroll
        for (int mt = 0; mt < 2; ++mt)
#pragma unroll
            for (int nt = 0; nt < 2; ++nt)
                acc[mt][nt] = (f32x4v){0.f, 0.f, 0.f, 0.f};

#pragma unroll
        for (int ks = 0; ks < 8; ++ks) {
            short8 Bh[2], Bl[2];
#pragma unroll
            for (int nt = 0; nt < 2; ++nt) {
                int col = nt * 16 + lr;
                int kgs = (ks * 4 + quad) ^ col;
                Bh[nt] = smem[cur][col * 32 + kgs];
                Bl[nt] = smem[cur][1024 + col * 32 + kgs];
            }
#pragma unroll
            for (int mt = 0; mt < 2; ++mt)
#pragma unroll
                for (int nt = 0; nt < 2; ++nt) {
                    f32x4v a = acc[mt][nt];
                    a = __builtin_amdgcn_mfma_f32_16x16x32_bf16(Ah[mt][ks], Bh[nt], a, 0, 0, 0);
                    a = __builtin_amdgcn_mfma_f32_16x16x32_bf16(Ah[mt][ks], Bl[nt], a, 0, 0, 0);
                    a = __builtin_amdgcn_mfma_f32_16x16x32_bf16(Al[mt][ks], Bh[nt], a, 0, 0, 0);
                    acc[mt][nt] = a;
                }
        }

        // d = fma(-2, dot, fl(sz+se)) == fl(fl(sz+se) - 2*dot) exactly
        const int colBase = slabBase + ch * 32;
#pragma unroll
        for (int nt = 0; nt < 2; ++nt) {
            const int colg = colBase + nt * 16 + lr;
            const float sec = nt ? sec1 : sec0;
#pragma unroll
            for (int mt = 0; mt < 2; ++mt)
#pragma unroll
                for (int rr = 0; rr < 4; ++rr) {
                    float szse = __fadd_rn(szr[mt][rr], sec);
                    float d = fmaf(-2.0f, acc[mt][nt][rr], szse);
                    if (d < minv[mt][rr]) {   // strict <: first index wins
                        minv[mt][rr] = d;
                        mini[mt][rr] = colg;
                    }
                }
        }
        __syncthreads();   // prefetch landed + cur consumed
    }

    // reduce across the 16 lanes (lr) that share each output row
#pragma unroll
    for (int st = 1; st < 16; st <<= 1) {
#pragma unroll
        for (int mt = 0; mt < 2; ++mt)
#pragma unroll
            for (int rr = 0; rr < 4; ++rr) {
                float ov = __shfl_xor(minv[mt][rr], st);
                int oi = __shfl_xor(mini[mt][rr], st);
                if (ov < minv[mt][rr] ||
                    (ov == minv[mt][rr] && oi < mini[mt][rr])) {
                    minv[mt][rr] = ov;
                    mini[mt][rr] = oi;
                }
            }
    }
    if (lr == 0) {
#pragma unroll
        for (int mt = 0; mt < 2; ++mt)
#pragma unroll
            for (int rr = 0; rr < 4; ++rr) {
                int row = rowBase + mt * 16 + quad * 4 + rr;
                pval[(size_t)row * 8 + slab] = minv[mt][rr];
                pidx[(size_t)row * 8 + slab] = mini[mt][rr];
            }
    }
}

// ---------------------------------------------------------------- K3a:
// per-token: reduce 8 slab partials -> final index; rotation scalars;
// per-block loss partial.
__global__ __launch_bounds__(256) void k3a_token(
    const float* __restrict__ z_flat, const float* __restrict__ emb,
    const float* __restrict__ pval, const int* __restrict__ pidx,
    float* __restrict__ alpha, float* __restrict__ beta,
    int* __restrict__ idxf, float* __restrict__ out,
    float* __restrict__ lpart) {
    __shared__ float red[4];
    const int w = threadIdx.x >> 6, lane = threadIdx.x & 63;
    const int t = blockIdx.x * 4 + w;

    float bv = INFINITY;
    int bi = 0x7fffffff;
    if (lane < 8) {
        bv = pval[(size_t)t * 8 + lane];
        bi = pidx[(size_t)t * 8 + lane];
    }
#pragma unroll
    for (int st = 1; st < 8; st <<= 1) {
        float ov = __shfl_xor(bv, st);
        int oi = __shfl_xor(bi, st);
        if (ov < bv || (ov == bv && oi < bi)) { bv = ov; bi = oi; }
    }
    const int best = __shfl(bi, 0);

    const float4 zv = *(const float4*)(z_flat + (size_t)t * 256 + lane * 4);
    const float4 ev = *(const float4*)(emb + (size_t)best * 256 + lane * 4);
    float szs = zv.x * zv.x + zv.y * zv.y + zv.z * zv.z + zv.w * zv.w;
    float ses = ev.x * ev.x + ev.y * ev.y + ev.z * ev.z + ev.w * ev.w;
    float zes = zv.x * ev.x + zv.y * ev.y + zv.z * ev.z + zv.w * ev.w;
    float dx = zv.x - ev.x, dy = zv.y - ev.y, dz = zv.z - ev.z, dw = zv.w - ev.w;
    float sqs = dx * dx + dy * dy + dz * dz + dw * dw;
#pragma unroll
    for (int m = 1; m < 64; m <<= 1) {
        szs += __shfl_xor(szs, m);
        ses += __shfl_xor(ses, m);
        zes += __shfl_xor(zes, m);
        sqs += __shfl_xor(sqs, m);
    }
    if (lane == 0) {
        float ns = sqrtf(szs), nt = sqrtf(ses);
        float inv_s = 1.0f / (ns + EPSV);
        float inv_t = 1.0f / (nt + EPSV);
        float s2 = szs * inv_s;                      // z . u
        float su = szs * inv_s * inv_s;
        float sq = ses * inv_t * inv_t;
        float uq = zes * inv_s * inv_t;
        float nw = sqrtf(su + sq + 2.0f * uq);
        float inv_w = 1.0f / (nw + EPSV);
        float s1 = (s2 + zes * inv_t) * inv_w;       // z . w_
        float scale = nt * inv_s;
        float a = scale * (1.0f - 2.0f * s1 * inv_w * inv_s);
        float bb = scale * inv_t * 2.0f * (s2 - s1 * inv_w);
        alpha[t] = a;
        beta[t] = bb;
        idxf[t] = best;
        out[2097153 + t] = (float)best;
        red[w] = sqs;
    }
    __syncthreads();
    if (threadIdx.x == 0)
        lpart[blockIdx.x] = red[0] + red[1] + red[2] + red[3];
}

// ---------------------------------------------------------------- K3b:
// z_q = alpha[t]*z + beta[t]*emb[idx[t]]; block 0 also writes the loss.
// 4 elems/thread (same c, tokens t0..t0+3), float4 I/O, 2048 blocks.
__global__ __launch_bounds__(256) void k3b_zq(
    const float* __restrict__ zin, const float* __restrict__ emb,
    const float* __restrict__ alpha, const float* __restrict__ beta,
    const int* __restrict__ idxf, const float* __restrict__ lpart,
    float* __restrict__ out) {
    if (blockIdx.x == 0) {             // ---- loss reduction
        __shared__ float red[4];
        const int tid = threadIdx.x;
        float s = 0.0f;
        for (int i = tid; i < 2048; i += 256) s += lpart[i];
#pragma unroll
        for (int m = 1; m < 64; m <<= 1) s += __shfl_xor(s, m);
        if ((tid & 63) == 0) red[tid >> 6] = s;
        __syncthreads();
        if (tid == 0)
            out[2097152] = 1.25f * (red[0] + red[1] + red[2] + red[3]) *
                           (1.0f / 2097152.0f);
    }
    const int i4 = (blockIdx.x * 256 + threadIdx.x) * 4;
    const int c = (i4 >> 10) & 255;
    const int t0 = ((i4 >> 18) << 10) | (i4 & 1023);   // tokens t0..t0+3
    const float4 zv = *(const float4*)(zin + i4);
    const float4 av = *(const float4*)(alpha + t0);
    const float4 bv = *(const float4*)(beta + t0);
    const int4  iv = *(const int4*)(idxf + t0);
    float4 o;
    o.x = av.x * zv.x + bv.x * emb[(size_t)iv.x * 256 + c];
    o.y = av.y * zv.y + bv.y * emb[(size_t)iv.y * 256 + c];
    o.z = av.z * zv.z + bv.z * emb[(size_t)iv.z * 256 + c];
    o.w = av.w * zv.w + bv.w * emb[(size_t)iv.w * 256 + c];
    *(float4*)(out + i4) = o;
}

// ----------------------------------------------------------------
extern "C" void kernel_launch(void* const* d_in, const int* in_sizes, int n_in,
                              void* d_out, int out_size, void* d_ws,
                              size_t ws_size, hipStream_t stream) {
    (void)in_sizes; (void)n_in; (void)out_size; (void)ws_size;
    const float* zin = (const float*)d_in[0];
    const float* cb  = (const float*)d_in[1];
    const float* Wm  = (const float*)d_in[2];
    float* out = (float*)d_out;
    char* ws = (char*)d_ws;

    float*          z_flat = (float*)(ws + 0);                     //  8 MB
    unsigned short* zh     = (unsigned short*)(ws + 8388608);      //  4 MB
    unsigned short* zl     = (unsigned short*)(ws + 12582912);     //  4 MB
    float*          emb    = (float*)(ws + 16777216);              // 16 MB
    unsigned short* eh     = (unsigned short*)(ws + 33554432);     //  8 MB
    unsigned short* el     = (unsigned short*)(ws + 41943040);     //  8 MB
    float*          sz     = (float*)(ws + 50331648);              // 32 KB
    float*          se0    = (float*)(ws + 50364416);              // 64 KB
    float*          se1    = (float*)(ws + 50429952);              // 64 KB
    float*          pval   = (float*)(ws + 50495488);              // 256 KB
    int*            pidx   = (int*)(ws + 50757632);                // 256 KB
    float*          alpha  = (float*)(ws + 51019776);              // 32 KB
    float*          beta   = (float*)(ws + 51052544);              // 32 KB
    int*            idxf   = (int*)(ws + 51085312);                // 32 KB
    float*          lpart  = (float*)(ws + 51118080);              //  8 KB
    unsigned short* wh     = (unsigned short*)(ws + 51126272);     // 128 KB
    unsigned short* wl     = (unsigned short*)(ws + 51257344);     // 128 KB

    fW_pre<<<64, 256, 0, stream>>>(Wm, wh, wl);
    k0c_fz<<<384, 256, 0, stream>>>(cb, wh, wl, emb, eh, el, se0, se1,
                                    zin, z_flat, zh, zl, sz);
    k1_dist_argmin<<<512, 256, 0, stream>>>(zh, zl, eh, el, sz,
                                            se0, se1, pval, pidx);
    k3a_token<<<2048, 256, 0, stream>>>(z_flat, emb, pval, pidx, alpha, beta,
                                        idxf, out, lpart);
    k3b_zq<<<2048, 256, 0, stream>>>(zin, emb, alpha, beta, idxf, lpart, out);
}